// Round 7
// baseline (12418.428 us; speedup 1.0000x reference)
//
#include <hip/hip_runtime.h>
#include <stdint.h>

#define T_STEPS 4096
#define HID     768
#define G3      2304      // 3*HID
#define NBLK    256       // one wave per block, 3 units each (256*3 = 768)
#define NTHR    64
#define UPB     3

// ---------------- threefry2x32 (matches jax._src.prng exactly) ----------------
__device__ __forceinline__ void threefry2x32(uint32_t k0, uint32_t k1,
                                             uint32_t x0, uint32_t x1,
                                             uint32_t* o0, uint32_t* o1) {
  uint32_t ks[3] = {k0, k1, k0 ^ k1 ^ 0x1BD11BDAu};
  x0 += ks[0]; x1 += ks[1];
  const int r0[4] = {13, 15, 26, 6};
  const int r1[4] = {17, 29, 16, 24};
#pragma unroll
  for (int i = 0; i < 5; ++i) {
    const int* rr = (i & 1) ? r1 : r0;
#pragma unroll
    for (int j = 0; j < 4; ++j) {
      x0 += x1;
      x1 = (x1 << rr[j]) | (x1 >> (32 - rr[j]));
      x1 ^= x0;
    }
    x0 += ks[(i + 1) % 3];
    x1 += ks[(i + 2) % 3] + (uint32_t)(i + 1);
  }
  *o0 = x0; *o1 = x1;
}

__device__ __forceinline__ float gumbel_from_bits(uint32_t bits) {
  float f = __uint_as_float((bits >> 9) | 0x3f800000u) - 1.0f;
  float u = fmaxf(f, 1.17549435e-38f);
  return -logf(-logf(u));
}

// ---- init: pair buffer 0 = (h0, tag 0), buffer 1 = tag -1 ----------------------
__global__ void init_pairs(const float* __restrict__ h0,
                           unsigned long long* __restrict__ pairs) {
  int j = threadIdx.x;
  if (j < HID) {
    pairs[j]       = (unsigned long long)__float_as_uint(h0[j]);  // tag 0 high word
    pairs[HID + j] = 0xFFFFFFFF00000000ull;                       // tag -1
  }
}

// ---------------- GEMM: xi = inputs(4096x768) @ Wi(768x2304) + bi  (fp32) ------
__launch_bounds__(256)
__global__ void gemm_xi(const float* __restrict__ A, const float* __restrict__ B,
                        const float* __restrict__ bias, float* __restrict__ C) {
  const int N = G3, K = HID;
  __shared__ __align__(16) float As[8][128];
  __shared__ __align__(16) float Bs[8][128];
  int tid = threadIdx.x;
  int bn = blockIdx.x * 128;
  int bm = blockIdx.y * 128;
  int tx = tid & 15, ty = tid >> 4;

  float acc[8][8];
#pragma unroll
  for (int i = 0; i < 8; ++i)
#pragma unroll
    for (int j = 0; j < 8; ++j) acc[i][j] = 0.f;

  const int ar = tid >> 1;
  const int ac = (tid & 1) * 4;
  const int br = tid >> 5;
  const int bc = (tid & 31) * 4;
  const float* Aptr = A + (size_t)(bm + ar) * K + ac;
  const float* Bptr = B + (size_t)br * N + bn + bc;

  for (int k0 = 0; k0 < K; k0 += 8) {
    float4 av = *(const float4*)(Aptr + k0);
    float4 bv = *(const float4*)(Bptr + (size_t)k0 * N);
    As[ac + 0][ar] = av.x; As[ac + 1][ar] = av.y;
    As[ac + 2][ar] = av.z; As[ac + 3][ar] = av.w;
    *(float4*)&Bs[br][bc] = bv;
    __syncthreads();
#pragma unroll
    for (int kk = 0; kk < 8; ++kk) {
      float a[8], b[8];
      *(float4*)&a[0] = *(const float4*)&As[kk][ty * 8];
      *(float4*)&a[4] = *(const float4*)&As[kk][ty * 8 + 4];
      *(float4*)&b[0] = *(const float4*)&Bs[kk][tx * 8];
      *(float4*)&b[4] = *(const float4*)&Bs[kk][tx * 8 + 4];
#pragma unroll
      for (int i = 0; i < 8; ++i)
#pragma unroll
        for (int j = 0; j < 8; ++j) acc[i][j] = fmaf(a[i], b[j], acc[i][j]);
    }
    __syncthreads();
  }
#pragma unroll
  for (int i = 0; i < 8; ++i) {
    float* crow = C + (size_t)(bm + ty * 8 + i) * N + bn + tx * 8;
    const float* brow = bias + bn + tx * 8;
#pragma unroll
    for (int j = 0; j < 8; ++j) crow[j] = acc[i][j] + brow[j];
  }
}

// ---------------- persistent GRU scan: 1 wave / 3 units, no LDS, no barriers -----
// Block b (one wave) owns units u0..u0+2 (u0=3b). Lane l polls pairs {64i+l}
// (12 coalesced 512B sweeps, got-mask early-exit) and holds Wh rows {64i+l} for
// the block's 9 columns in 108 VGPRs (U=3 chosen so ~160 live regs fit without
// spill; waves_per_eu(1,1) hands the wave the whole RF -- only 1 wave/CU runs).
// 108 FMA + 54-shfl butterfly; lanes 0..2 compute gates, publish (value,tag)
// FIRST (visibility latency starts earliest), then write y.
// Race-freedom: a wave stores tag t+1 only after its full poll of tag t.
__global__ __launch_bounds__(NTHR) __attribute__((amdgpu_waves_per_eu(1, 1)))
void gru_scan(const float* __restrict__ xi, const float* __restrict__ Wh,
              const float* __restrict__ bhn, const float* __restrict__ h0,
              unsigned long long* __restrict__ pairs,
              float* __restrict__ y) {
  const int lane = threadIdx.x;
  const int u0   = blockIdx.x * UPB;

  // weights: w[d*12+i] = Wh[64i+lane][ (d/3)*HID + u0 + (d%3) ],  d = gate*3+unit
  float w[108];
#pragma unroll
  for (int i = 0; i < 12; ++i) {
    const float* row = Wh + (size_t)(64 * i + lane) * G3;
#pragma unroll
    for (int g = 0; g < 3; ++g)
#pragma unroll
      for (int j = 0; j < 3; ++j)
        w[(g * 3 + j) * 12 + i] = row[g * HID + u0 + j];
  }

  // lane j<3 owns unit u0+j
  float bhn_u = 0.f, h_cur = 0.f;
  if (lane < UPB) {
    bhn_u = bhn[u0 + lane];
    h_cur = h0[u0 + lane];
  }

  for (int t = 0; t < T_STEPS; ++t) {
    const unsigned long long* buf = pairs + (size_t)(t & 1) * HID;

    // xi prefetch for lanes 0..2 (issued before the poll; completes under it)
    float xr = 0.f, xz = 0.f, xn = 0.f;
    if (lane < UPB) {
      const float* xrow = xi + (size_t)t * G3 + u0 + lane;
      xr = xrow[0];
      xz = xrow[HID];
      xn = xrow[2 * HID];
    }

    // poll the 12 owned pairs; issue outstanding ones in parallel, then check
    float hval[12];
    unsigned int got = 0;
    while (got != 0xFFFu) {
      unsigned long long v[12];
#pragma unroll
      for (int i = 0; i < 12; ++i)
        if (!(got & (1u << i)))
          v[i] = __hip_atomic_load(&buf[64 * i + lane], __ATOMIC_RELAXED,
                                   __HIP_MEMORY_SCOPE_AGENT);
#pragma unroll
      for (int i = 0; i < 12; ++i)
        if (!(got & (1u << i)) &&
            (unsigned int)(v[i] >> 32) == (unsigned int)t) {
          hval[i] = __uint_as_float((unsigned int)v[i]);
          got |= (1u << i);
        }
    }

    // 108 FMA: 12 h-chunks x 9 columns, independent chains per column
    float acc[9];
#pragma unroll
    for (int d = 0; d < 9; ++d) acc[d] = 0.f;
#pragma unroll
    for (int i = 0; i < 12; ++i) {
      float hv = hval[i];
#pragma unroll
      for (int d = 0; d < 9; ++d) acc[d] = fmaf(hv, w[d * 12 + i], acc[d]);
    }
    // butterfly: every lane ends with all 9 full dots
#pragma unroll
    for (int m = 1; m < 64; m <<= 1) {
#pragma unroll
      for (int d = 0; d < 9; ++d) acc[d] += __shfl_xor(acc[d], m, 64);
    }

    // lanes 0..2: gates + publish-first
    if (lane < UPB) {
      float r = 1.f / (1.f + expf(-(xr + acc[lane])));
      float z = 1.f / (1.f + expf(-(xz + acc[3 + lane])));
      float n = tanhf(xn + r * (acc[6 + lane] + bhn_u));
      h_cur = (1.f - z) * n + z * h_cur;
      unsigned long long pv =
          (((unsigned long long)(unsigned int)(t + 1)) << 32) | __float_as_uint(h_cur);
      __hip_atomic_store(&pairs[(size_t)((t + 1) & 1) * HID + u0 + lane], pv,
                         __ATOMIC_RELAXED, __HIP_MEMORY_SCOPE_AGENT);
      y[(size_t)t * HID + u0 + lane] = h_cur;
    }
  }
}

// ---------------- decode: out = y@Wd + bd ; action = argmax(out[:, :2] + gumbel) ---
__launch_bounds__(256)
__global__ void decode_out(const float* __restrict__ y, const float* __restrict__ Wd,
                           const float* __restrict__ bd, float* __restrict__ out) {
  int tid = threadIdx.x;
  int lane = tid & 63;
  int wid = tid >> 6;
  int r = blockIdx.x * 4 + wid;
  const float* yr = y + (size_t)r * HID;

  float acc0 = 0.f, acc1 = 0.f, acc2 = 0.f, acc3 = 0.f;
#pragma unroll
  for (int i = 0; i < 12; ++i) {
    int k = lane + 64 * i;
    float yv = yr[k];
    float4 wd = *(const float4*)&Wd[(size_t)k * 4];
    acc0 = fmaf(yv, wd.x, acc0);
    acc1 = fmaf(yv, wd.y, acc1);
    acc2 = fmaf(yv, wd.z, acc2);
    acc3 = fmaf(yv, wd.w, acc3);
    if (r == T_STEPS - 1) out[20480 + k] = yv;   // final_h
  }
#pragma unroll
  for (int m = 32; m >= 1; m >>= 1) {
    acc0 += __shfl_xor(acc0, m, 64);
    acc1 += __shfl_xor(acc1, m, 64);
    acc2 += __shfl_xor(acc2, m, 64);
    acc3 += __shfl_xor(acc3, m, 64);
  }
  if (lane == 0) {
    float o0 = acc0 + bd[0], o1 = acc1 + bd[1], o2 = acc2 + bd[2], o3 = acc3 + bd[3];
    out[(size_t)r * 4 + 0] = o0;
    out[(size_t)r * 4 + 1] = o1;
    out[(size_t)r * 4 + 2] = o2;
    out[(size_t)r * 4 + 3] = o3;

    // jax PRNG, threefry_partitionable (verified round 2)
    uint32_t ak0, ak1;
    threefry2x32(0u, 42u, 0u, 1u, &ak0, &ak1);
    uint32_t s0, s1;
    threefry2x32(ak0, ak1, 0u, (uint32_t)(2 * r), &s0, &s1);
    uint32_t g0bits = s0 ^ s1;
    threefry2x32(ak0, ak1, 0u, (uint32_t)(2 * r + 1), &s0, &s1);
    uint32_t g1bits = s0 ^ s1;

    float gg0 = gumbel_from_bits(g0bits);
    float gg1 = gumbel_from_bits(g1bits);
    int action = (o1 + gg1 > o0 + gg0) ? 1 : 0;
    out[16384 + r] = (float)action;
  }
}

// ---------------- launch -----------------------------------------------------------
extern "C" void kernel_launch(void* const* d_in, const int* in_sizes, int n_in,
                              void* d_out, int out_size, void* d_ws, size_t ws_size,
                              hipStream_t stream) {
  const float* inputs = (const float*)d_in[0];
  const float* h0     = (const float*)d_in[1];
  const float* Wi     = (const float*)d_in[2];
  const float* bi     = (const float*)d_in[3];
  const float* Wh     = (const float*)d_in[4];
  const float* bhn    = (const float*)d_in[5];
  const float* Wd     = (const float*)d_in[6];
  const float* bd     = (const float*)d_in[7];
  float* out = (float*)d_out;

  char* ws = (char*)d_ws;
  unsigned long long* pairs = (unsigned long long*)ws;              // 2*768*8 = 12 KB
  float* xi = (float*)(ws + 16384);                                 // 4096*2304*4
  float* y  = (float*)(ws + 16384 + (size_t)T_STEPS * G3 * 4);      // 4096*768*4

  hipLaunchKernelGGL(init_pairs, dim3(1), dim3(HID), 0, stream, h0, pairs);
  hipLaunchKernelGGL(gemm_xi, dim3(G3 / 128, T_STEPS / 128), dim3(256), 0, stream,
                     inputs, Wi, bi, xi);

  {
    const float* xi_c = xi;
    const float* wh_c = Wh;
    const float* bhn_c = bhn;
    const float* h0_c = h0;
    unsigned long long* pr = pairs;
    float* y_p = y;
    void* args[] = { (void*)&xi_c, (void*)&wh_c, (void*)&bhn_c, (void*)&h0_c,
                     (void*)&pr, (void*)&y_p };
    hipError_t e = hipLaunchCooperativeKernel((const void*)gru_scan, dim3(NBLK),
                                              dim3(NTHR), args, 0, stream);
    if (e != hipSuccess) {
      hipLaunchKernelGGL(gru_scan, dim3(NBLK), dim3(NTHR), 0, stream,
                         xi_c, wh_c, bhn_c, h0_c, pr, y_p);
    }
  }

  hipLaunchKernelGGL(decode_out, dim3(T_STEPS / 4), dim3(256), 0, stream, y, Wd, bd, out);
}